// Round 12
// baseline (42.923 us; speedup 1.0000x reference)
//
#include <hip/hip_runtime.h>
#include <math.h>

#define CEPS 1e-8f

typedef __attribute__((ext_vector_type(8))) short bf16x8;
typedef __attribute__((ext_vector_type(4))) float f32x4;
typedef __attribute__((ext_vector_type(4))) unsigned int u32x4;
typedef __attribute__((ext_vector_type(2))) unsigned int u32x2;

__device__ __forceinline__ unsigned short f2bf(float f) {
    unsigned u = __builtin_bit_cast(unsigned, f);
    u += 0x7fffu + ((u >> 16) & 1u);            // round-nearest-even
    return (unsigned short)(u >> 16);
}

// pack two f32 -> two bf16 (round-half-up) in one u32
__device__ __forceinline__ unsigned pk2(float a, float b) {
    unsigned ua = __builtin_bit_cast(unsigned, a) + 0x8000u;
    unsigned ub = __builtin_bit_cast(unsigned, b) + 0x8000u;
    return (ua >> 16) | (ub & 0xFFFF0000u);
}

__device__ __forceinline__ bf16x8 cvt8(const float4& lo, const float4& hi) {
    u32x4 r;
    r.x = pk2(lo.x, lo.y);
    r.y = pk2(lo.z, lo.w);
    r.z = pk2(hi.x, hi.y);
    r.w = pk2(hi.z, hi.w);
    return __builtin_bit_cast(bf16x8, r);
}

// Pack weights fp32 -> bf16, MFMA fragment layout [K/8][N][8].
__global__ __launch_bounds__(256)
void pack_all(const float* __restrict__ uW1, const float* __restrict__ uW2,
              const float* __restrict__ iW1, const float* __restrict__ iW2,
              unsigned short* __restrict__ o1, unsigned short* __restrict__ o2,
              unsigned short* __restrict__ o3, unsigned short* __restrict__ o4)
{
    int g = blockIdx.x * 256 + threadIdx.x;     // 32768 entries
    const float* src; unsigned short* dst; int N; int base;
    if (g < 16384)      { src = uW1; dst = o1; N = 256; base = 0;     }
    else if (g < 20480) { src = uW2; dst = o2; N = 128; base = 16384; }
    else if (g < 28672) { src = iW1; dst = o3; N = 256; base = 20480; }
    else                { src = iW2; dst = o4; N = 128; base = 28672; }
    int i = g - base;
    int kg = i / N, n = i - kg * N;
    unsigned short tmp[8];
    #pragma unroll
    for (int j = 0; j < 8; ++j)
        tmp[j] = f2bf(src[(kg * 8 + j) * N + n]);
    *reinterpret_cast<bf16x8*>(dst + ((size_t)i << 3)) =
        *reinterpret_cast<bf16x8*>(tmp);
}

// ---- fused towers, 32 rows/block, 512 threads (8 waves), 2 blocks/CU ----
// Waves 0-3: user tower.  Waves 4-7: item tower (concurrent).
// NO e-staging phase: GEMM1 A-fragments are loaded straight from the
// embedding table (8 K-contiguous bf16 == 32 contiguous table bytes) and
// packed to bf16 in-register. Gather overlaps weights+MFMA per-wave.
// Swapped-operand MFMA: D[wcol][erow] = mfma(Wfrag, efrag).

// LDS fragment read: 8 K-contiguous bf16 of row (ni*16+l15) at k-slice l4.
template<int KB>
__device__ __forceinline__ bf16x8 loadA(const unsigned short* s, int ks, int ni,
                                        int l15, int l4)
{
    int row = ni * 16 + l15;
    int byte = row * (KB * 2) + ks * 64 + l4 * 16;
    byte ^= (row & 7) << 4;
    return *reinterpret_cast<const bf16x8*>(
               reinterpret_cast<const char*>(s) + byte);
}

// GEMM1 direct: wave owns w-cols [wl*64,+64) (4 frags), 32 e-rows (2 frags).
// e loaded per-wave from table; F fields; K1 = 64*F; NKS = 2*F.
template<int F>
__device__ __forceinline__ void gemm1_direct(
    const int* __restrict__ ids, const float* __restrict__ table,
    unsigned short* h_s,
    const unsigned short* __restrict__ W1p, const float* __restrict__ b1,
    int row0, int l15, int l4, int wl, const bf16x8 (&w0)[4])
{
    constexpr int NKS = 2 * F;
    f32x4 acc[4][2];
    #pragma unroll
    for (int mi = 0; mi < 4; ++mi)
        #pragma unroll
        for (int ni = 0; ni < 2; ++ni) acc[mi][ni] = (f32x4){0.f, 0.f, 0.f, 0.f};

    // per-lane ids: rows l15 and 16+l15, all F fields
    int idbuf[2][F];
    #pragma unroll
    for (int ni = 0; ni < 2; ++ni)
        #pragma unroll
        for (int g = 0; g < F / 4; ++g) {
            int4 t = *reinterpret_cast<const int4*>(
                         &ids[(row0 + ni * 16 + l15) * F + g * 4]);
            idbuf[ni][g * 4 + 0] = t.x;
            idbuf[ni][g * 4 + 1] = t.y;
            idbuf[ni][g * 4 + 2] = t.z;
            idbuf[ni][g * 4 + 3] = t.w;
        }

    const unsigned short* Wbase = W1p + ((l4 * 256 + wl * 64 + l15) << 3);
    bf16x8 wf[2][4];
    #pragma unroll
    for (int mi = 0; mi < 4; ++mi) wf[0][mi] = w0[mi];

    float4 eraw[2][2][2];
    #pragma unroll
    for (int ni = 0; ni < 2; ++ni) {
        const float* p = table + (size_t)idbuf[ni][0] * 64 + l4 * 8;
        eraw[0][ni][0] = *reinterpret_cast<const float4*>(p);
        eraw[0][ni][1] = *reinterpret_cast<const float4*>(p + 4);
    }

    #pragma unroll
    for (int ks = 0; ks < NKS; ++ks) {
        if (ks + 1 < NKS) {
            // prefetch next e (direct from table) and next weights
            #pragma unroll
            for (int ni = 0; ni < 2; ++ni) {
                const float* p = table
                    + (size_t)idbuf[ni][(ks + 1) >> 1] * 64
                    + ((ks + 1) & 1) * 32 + l4 * 8;
                eraw[(ks + 1) & 1][ni][0] = *reinterpret_cast<const float4*>(p);
                eraw[(ks + 1) & 1][ni][1] = *reinterpret_cast<const float4*>(p + 4);
            }
            #pragma unroll
            for (int mi = 0; mi < 4; ++mi)
                wf[(ks + 1) & 1][mi] = *reinterpret_cast<const bf16x8*>(
                    Wbase + (ks + 1) * 8192 + (mi << 7));
        }
        bf16x8 ef[2];
        #pragma unroll
        for (int ni = 0; ni < 2; ++ni)
            ef[ni] = cvt8(eraw[ks & 1][ni][0], eraw[ks & 1][ni][1]);
        __builtin_amdgcn_s_setprio(1);
        #pragma unroll
        for (int mi = 0; mi < 4; ++mi)
            #pragma unroll
            for (int ni = 0; ni < 2; ++ni)
                acc[mi][ni] = __builtin_amdgcn_mfma_f32_16x16x32_bf16(
                                  wf[ks & 1][mi], ef[ni], acc[mi][ni], 0, 0, 0);
        __builtin_amdgcn_s_setprio(0);
    }
    // epilogue: bias + relu; lane holds 4 consecutive w-cols of one row -> b64
    #pragma unroll
    for (int mi = 0; mi < 4; ++mi) {
        const float4 bb = *reinterpret_cast<const float4*>(
                              &b1[wl * 64 + mi * 16 + l4 * 4]);
        #pragma unroll
        for (int ni = 0; ni < 2; ++ni) {
            float v0 = acc[mi][ni][0] + bb.x; v0 = v0 > 0.f ? v0 : 0.f;
            float v1 = acc[mi][ni][1] + bb.y; v1 = v1 > 0.f ? v1 : 0.f;
            float v2 = acc[mi][ni][2] + bb.z; v2 = v2 > 0.f ? v2 : 0.f;
            float v3 = acc[mi][ni][3] + bb.w; v3 = v3 > 0.f ? v3 : 0.f;
            u32x2 d;
            d.x = f2bf(v0) | ((unsigned)f2bf(v1) << 16);
            d.y = f2bf(v2) | ((unsigned)f2bf(v3) << 16);
            int row = ni * 16 + l15;
            int w0c = wl * 64 + mi * 16 + l4 * 4;
            int byte = (row * 256 + w0c) * 2;
            byte ^= (row & 7) << 4;
            *reinterpret_cast<u32x2*>(reinterpret_cast<char*>(h_s) + byte) = d;
        }
    }
}

// GEMM2 (swapped): wave owns out-cols [wl*32, +32) (2 frags), 32 rows (2 frags).
__device__ __forceinline__ void gemm2(
    const unsigned short* h_s, const unsigned short* __restrict__ W2p,
    f32x4 (&acc)[2][2], int l15, int l4, int wl, const bf16x8 (&w01)[2][2])
{
    #pragma unroll
    for (int mi = 0; mi < 2; ++mi)
        #pragma unroll
        for (int ni = 0; ni < 2; ++ni) acc[mi][ni] = (f32x4){0.f, 0.f, 0.f, 0.f};

    const unsigned short* Wbase = W2p + ((l4 * 128 + wl * 32 + l15) << 3);
    bf16x8 wf[3][2], hf[2][2];
    #pragma unroll
    for (int mi = 0; mi < 2; ++mi) {
        wf[0][mi] = w01[0][mi];
        wf[1][mi] = w01[1][mi];
    }
    #pragma unroll
    for (int ni = 0; ni < 2; ++ni) hf[0][ni] = loadA<256>(h_s, 0, ni, l15, l4);

    #pragma unroll
    for (int ks = 0; ks < 8; ++ks) {
        if (ks + 2 < 8) {
            #pragma unroll
            for (int mi = 0; mi < 2; ++mi)
                wf[(ks + 2) % 3][mi] = *reinterpret_cast<const bf16x8*>(
                    Wbase + (ks + 2) * 4096 + (mi << 7));
        }
        if (ks + 1 < 8) {
            #pragma unroll
            for (int ni = 0; ni < 2; ++ni)
                hf[(ks + 1) & 1][ni] = loadA<256>(h_s, ks + 1, ni, l15, l4);
        }
        __builtin_amdgcn_s_setprio(1);
        #pragma unroll
        for (int mi = 0; mi < 2; ++mi)
            #pragma unroll
            for (int ni = 0; ni < 2; ++ni)
                acc[mi][ni] = __builtin_amdgcn_mfma_f32_16x16x32_bf16(
                                  wf[ks % 3][mi], hf[ks & 1][ni], acc[mi][ni], 0, 0, 0);
        __builtin_amdgcn_s_setprio(0);
    }
}

__global__ __launch_bounds__(512, 4)
void fused_sbc(const int* __restrict__ user_ids,  const int* __restrict__ item_ids,
               const float* __restrict__ user_table, const float* __restrict__ item_table,
               const unsigned short* __restrict__ uW1p, const float* __restrict__ ub1,
               const unsigned short* __restrict__ uW2p, const float* __restrict__ ub2,
               const unsigned short* __restrict__ iW1p, const float* __restrict__ ib1,
               const unsigned short* __restrict__ iW2p, const float* __restrict__ ib2,
               const float* __restrict__ sw, float* __restrict__ out,
               int B, int nn1)
{
    __shared__ __align__(16) unsigned short smem[25600];   // 51.2 KB
    unsigned short* h_u = smem;                  // [32][256] 16 KB
    unsigned short* h_i = smem + 8192;           // [32][256] 16 KB
    float* V_lds = reinterpret_cast<float*>(smem + 16384); // [32][132] 16.9 KB
    float* red   = reinterpret_cast<float*>(
                       reinterpret_cast<char*>(smem) + 49664); // [4][32][3]

    const int tid  = threadIdx.x;
    const int lane = tid & 63;
    const int w    = tid >> 6;
    const int l15  = lane & 15, l4 = lane >> 4;
    const int role = w >> 2;                     // 0 = user, 1 = item
    const int wl   = w & 3;
    const int row0 = blockIdx.x * 32;

    const unsigned short* W1sel = role ? iW1p : uW1p;
    const unsigned short* W2sel = role ? iW2p : uW2p;

    // preload ks=0 GEMM1 weight fragments
    bf16x8 w1pre[4];
    {
        const unsigned short* base = W1sel + ((l4 * 256 + wl * 64 + l15) << 3);
        #pragma unroll
        for (int mi = 0; mi < 4; ++mi)
            w1pre[mi] = *reinterpret_cast<const bf16x8*>(base + (mi << 7));
    }

    // ---- GEMM1 with e streamed directly from the tables (no staging) ----
    if (role == 0)
        gemm1_direct<8>(user_ids, user_table, h_u, uW1p, ub1,
                        row0, l15, l4, wl, w1pre);
    else
        gemm1_direct<4>(item_ids, item_table, h_i, iW1p, ib1,
                        row0, l15, l4, wl, w1pre);

    // preload BOTH GEMM2 slots (in flight across barrier B2)
    bf16x8 w2pre[2][2];
    {
        const unsigned short* base = W2sel + ((l4 * 128 + wl * 32 + l15) << 3);
        #pragma unroll
        for (int s = 0; s < 2; ++s)
            #pragma unroll
            for (int mi = 0; mi < 2; ++mi)
                w2pre[s][mi] = *reinterpret_cast<const bf16x8*>(
                                   base + s * 4096 + (mi << 7));
    }
    __syncthreads();                             // B2: h_u, h_i ready

    f32x4 acc2[2][2];
    if (role == 0) gemm2(h_u, uW2p, acc2, l15, l4, wl, w2pre);
    else           gemm2(h_i, iW2p, acc2, l15, l4, wl, w2pre);

    // item waves: relu(V) -> V_lds + ||v||^2 partials
    if (role == 1) {
        float pv[2] = {0.f, 0.f};
        #pragma unroll
        for (int mi = 0; mi < 2; ++mi) {
            const int colb = wl * 32 + mi * 16 + l4 * 4;
            const float4 bv = *reinterpret_cast<const float4*>(&ib2[colb]);
            #pragma unroll
            for (int ni = 0; ni < 2; ++ni) {
                int row = ni * 16 + l15;
                float v0 = acc2[mi][ni][0] + bv.x; v0 = v0 > 0.f ? v0 : 0.f;
                float v1 = acc2[mi][ni][1] + bv.y; v1 = v1 > 0.f ? v1 : 0.f;
                float v2 = acc2[mi][ni][2] + bv.z; v2 = v2 > 0.f ? v2 : 0.f;
                float v3 = acc2[mi][ni][3] + bv.w; v3 = v3 > 0.f ? v3 : 0.f;
                float4 vv = {v0, v1, v2, v3};
                *reinterpret_cast<float4*>(&V_lds[row * 132 + colb]) = vv;
                pv[ni] += v0 * v0 + v1 * v1 + v2 * v2 + v3 * v3;
            }
        }
        #pragma unroll
        for (int ni = 0; ni < 2; ++ni) {
            pv[ni] += __shfl_xor(pv[ni], 16);
            pv[ni] += __shfl_xor(pv[ni], 32);
        }
        if (l4 == 0) {
            #pragma unroll
            for (int ni = 0; ni < 2; ++ni)
                red[(wl * 32 + ni * 16 + l15) * 3 + 2] = pv[ni];
        }
    }
    __syncthreads();                             // B3: V published

    // user waves: relu(U), dot + ||u||^2 partials
    if (role == 0) {
        float pd[2] = {0.f, 0.f}, pu[2] = {0.f, 0.f};
        #pragma unroll
        for (int mi = 0; mi < 2; ++mi) {
            const int colb = wl * 32 + mi * 16 + l4 * 4;
            const float4 bu = *reinterpret_cast<const float4*>(&ub2[colb]);
            #pragma unroll
            for (int ni = 0; ni < 2; ++ni) {
                int row = ni * 16 + l15;
                float u0 = acc2[mi][ni][0] + bu.x; u0 = u0 > 0.f ? u0 : 0.f;
                float u1 = acc2[mi][ni][1] + bu.y; u1 = u1 > 0.f ? u1 : 0.f;
                float u2 = acc2[mi][ni][2] + bu.z; u2 = u2 > 0.f ? u2 : 0.f;
                float u3 = acc2[mi][ni][3] + bu.w; u3 = u3 > 0.f ? u3 : 0.f;
                const float4 vv = *reinterpret_cast<const float4*>(
                                      &V_lds[row * 132 + colb]);
                pd[ni] += u0 * vv.x + u1 * vv.y + u2 * vv.z + u3 * vv.w;
                pu[ni] += u0 * u0 + u1 * u1 + u2 * u2 + u3 * u3;
            }
        }
        #pragma unroll
        for (int ni = 0; ni < 2; ++ni) {
            pd[ni] += __shfl_xor(pd[ni], 16);
            pd[ni] += __shfl_xor(pd[ni], 32);
            pu[ni] += __shfl_xor(pu[ni], 16);
            pu[ni] += __shfl_xor(pu[ni], 32);
        }
        if (l4 == 0) {
            #pragma unroll
            for (int ni = 0; ni < 2; ++ni) {
                red[(wl * 32 + ni * 16 + l15) * 3 + 0] = pd[ni];
                red[(wl * 32 + ni * 16 + l15) * 3 + 1] = pu[ni];
            }
        }
    }
    __syncthreads();                             // B4: partials in red

    // final reduce + y + scatter
    if (tid < 32) {
        int row = tid;
        float d = 0.f, su = 0.f, sv = 0.f;
        #pragma unroll
        for (int cg = 0; cg < 4; ++cg) {
            d  += red[(cg * 32 + row) * 3 + 0];
            su += red[(cg * 32 + row) * 3 + 1];
            sv += red[(cg * 32 + row) * 3 + 2];
        }
        float un = fmaxf(sqrtf(su), CEPS);
        float vn = fmaxf(sqrtf(sv), CEPS);
        int grow = row0 + row;
        float yv = d / (un * vn) - logf(sw[grow]);
        for (int j = 0; j < nn1; ++j) {
            int idx = grow - j;
            if (idx < 0) idx += B;
            out[idx * nn1 + j] = yv;
        }
    }
}

extern "C" void kernel_launch(void* const* d_in, const int* in_sizes, int n_in,
                              void* d_out, int out_size, void* d_ws, size_t ws_size,
                              hipStream_t stream)
{
    const int*   user_ids   = (const int*)  d_in[0];
    const int*   item_ids   = (const int*)  d_in[1];
    const float* sw         = (const float*)d_in[2];
    const float* user_table = (const float*)d_in[3];
    const float* item_table = (const float*)d_in[4];
    const float* uW1        = (const float*)d_in[5];
    const float* ub1        = (const float*)d_in[6];
    const float* uW2        = (const float*)d_in[7];
    const float* ub2        = (const float*)d_in[8];
    const float* iW1        = (const float*)d_in[9];
    const float* ib1        = (const float*)d_in[10];
    const float* iW2        = (const float*)d_in[11];
    const float* ib2        = (const float*)d_in[12];

    const int B   = in_sizes[2];       // 16384
    const int nn1 = out_size / B;      // n_neg + 1

    unsigned short* wp   = (unsigned short*)d_ws;
    unsigned short* uW1p = wp;               // 131072
    unsigned short* uW2p = wp + 131072;      // 32768
    unsigned short* iW1p = wp + 163840;      // 65536
    unsigned short* iW2p = wp + 229376;      // 32768
    float* out = (float*)d_out;

    pack_all<<<128, 256, 0, stream>>>(uW1, uW2, iW1, iW2,
                                      uW1p, uW2p, iW1p, iW2p);
    fused_sbc<<<B / 32, 512, 0, stream>>>(user_ids, item_ids,
                                          user_table, item_table,
                                          uW1p, ub1, uW2p, ub2,
                                          iW1p, ib1, iW2p, ib2,
                                          sw, out, B, nn1);
}

// Round 13
// 27.977 us; speedup vs baseline: 1.5342x; 1.5342x over previous
//
#include <hip/hip_runtime.h>
#include <math.h>

#define CEPS 1e-8f

typedef __attribute__((ext_vector_type(8))) short bf16x8;
typedef __attribute__((ext_vector_type(4))) float f32x4;
typedef __attribute__((ext_vector_type(4))) unsigned int u32x4;
typedef __attribute__((ext_vector_type(2))) unsigned int u32x2;

__device__ __forceinline__ unsigned short f2bf(float f) {
    unsigned u = __builtin_bit_cast(unsigned, f);
    u += 0x7fffu + ((u >> 16) & 1u);            // round-nearest-even
    return (unsigned short)(u >> 16);
}

// Pack weights fp32 -> bf16, MFMA fragment layout [K/8][N][8].
__global__ __launch_bounds__(256)
void pack_all(const float* __restrict__ uW1, const float* __restrict__ uW2,
              const float* __restrict__ iW1, const float* __restrict__ iW2,
              unsigned short* __restrict__ o1, unsigned short* __restrict__ o2,
              unsigned short* __restrict__ o3, unsigned short* __restrict__ o4)
{
    int g = blockIdx.x * 256 + threadIdx.x;     // 32768 entries
    const float* src; unsigned short* dst; int N; int base;
    if (g < 16384)      { src = uW1; dst = o1; N = 256; base = 0;     }
    else if (g < 20480) { src = uW2; dst = o2; N = 128; base = 16384; }
    else if (g < 28672) { src = iW1; dst = o3; N = 256; base = 20480; }
    else                { src = iW2; dst = o4; N = 128; base = 28672; }
    int i = g - base;
    int kg = i / N, n = i - kg * N;
    unsigned short tmp[8];
    #pragma unroll
    for (int j = 0; j < 8; ++j)
        tmp[j] = f2bf(src[(kg * 8 + j) * N + n]);
    *reinterpret_cast<bf16x8*>(dst + ((size_t)i << 3)) =
        *reinterpret_cast<bf16x8*>(tmp);
}

// ---- fused towers, 32 rows/block, 512 threads (8 waves), 2 blocks/CU ----
// Waves 0-3: user tower.  Waves 4-7: item tower (concurrent).
// Swapped-operand MFMA: D[wcol][erow] = mfma(Wfrag, efrag).
// Both weight-rotation slots preloaded BEFORE staging -> L2 warm-up hidden
// under the HBM gather phase.

template<int F>
__device__ __forceinline__ void stage_emb(const int* __restrict__ ids,
                                          const float* __restrict__ table,
                                          unsigned short* e_s, int row0, int tid)
{
    constexpr int FC = F * 8;                    // 16B chunks per row
    constexpr int IT = (32 * FC) / 512;
    int idv[IT];
    #pragma unroll
    for (int it = 0; it < IT; ++it) {
        int c = tid + it * 512;
        int r = c / FC, f = (c % FC) >> 3;
        idv[it] = ids[(row0 + r) * F + f];
    }
    #pragma unroll
    for (int it = 0; it < IT; ++it) {
        int c = tid + it * 512;
        int r = c / FC, rem = c % FC;
        const float* src = table + (size_t)idv[it] * 64 + (rem & 7) * 8;
        float4 aa = *reinterpret_cast<const float4*>(src);
        float4 bb = *reinterpret_cast<const float4*>(src + 4);
        u32x4 pk;
        pk.x = f2bf(aa.x) | ((unsigned)f2bf(aa.y) << 16);
        pk.y = f2bf(aa.z) | ((unsigned)f2bf(aa.w) << 16);
        pk.z = f2bf(bb.x) | ((unsigned)f2bf(bb.y) << 16);
        pk.w = f2bf(bb.z) | ((unsigned)f2bf(bb.w) << 16);
        int byte = r * (F * 128) + rem * 16;
        byte ^= (r & 7) << 4;
        *reinterpret_cast<u32x4*>(reinterpret_cast<char*>(e_s) + byte) = pk;
    }
}

// LDS fragment read: 8 K-contiguous bf16 of row (ni*16+l15) at k-slice l4.
template<int KB>
__device__ __forceinline__ bf16x8 loadA(const unsigned short* s, int ks, int ni,
                                        int l15, int l4)
{
    int row = ni * 16 + l15;
    int byte = row * (KB * 2) + ks * 64 + l4 * 16;
    byte ^= (row & 7) << 4;
    return *reinterpret_cast<const bf16x8*>(
               reinterpret_cast<const char*>(s) + byte);
}

// GEMM1 (swapped): wave owns w-cols [wl*64, +64) (4 frags), 32 e-rows (2 frags).
template<int K1>
__device__ __forceinline__ void gemm1(
    const unsigned short* e_s, unsigned short* h_s,
    const unsigned short* __restrict__ W1p, const float* __restrict__ b1,
    int l15, int l4, int wl, const bf16x8 (&w01)[2][4])
{
    constexpr int NKS = K1 / 32;
    f32x4 acc[4][2];
    #pragma unroll
    for (int mi = 0; mi < 4; ++mi)
        #pragma unroll
        for (int ni = 0; ni < 2; ++ni) acc[mi][ni] = (f32x4){0.f, 0.f, 0.f, 0.f};

    const unsigned short* Wbase = W1p + ((l4 * 256 + wl * 64 + l15) << 3);
    bf16x8 wf[3][4], ef[2][2];
    #pragma unroll
    for (int mi = 0; mi < 4; ++mi) {
        wf[0][mi] = w01[0][mi];
        wf[1][mi] = w01[1][mi];
    }
    #pragma unroll
    for (int ni = 0; ni < 2; ++ni) ef[0][ni] = loadA<K1>(e_s, 0, ni, l15, l4);

    #pragma unroll
    for (int ks = 0; ks < NKS; ++ks) {
        if (ks + 2 < NKS) {
            #pragma unroll
            for (int mi = 0; mi < 4; ++mi)
                wf[(ks + 2) % 3][mi] = *reinterpret_cast<const bf16x8*>(
                    Wbase + (ks + 2) * 8192 + (mi << 7));
        }
        if (ks + 1 < NKS) {
            #pragma unroll
            for (int ni = 0; ni < 2; ++ni)
                ef[(ks + 1) & 1][ni] = loadA<K1>(e_s, ks + 1, ni, l15, l4);
        }
        __builtin_amdgcn_s_setprio(1);
        #pragma unroll
        for (int mi = 0; mi < 4; ++mi)
            #pragma unroll
            for (int ni = 0; ni < 2; ++ni)
                acc[mi][ni] = __builtin_amdgcn_mfma_f32_16x16x32_bf16(
                                  wf[ks % 3][mi], ef[ks & 1][ni], acc[mi][ni], 0, 0, 0);
        __builtin_amdgcn_s_setprio(0);
    }
    // epilogue: bias + relu; lane holds 4 consecutive w-cols of one row -> b64
    #pragma unroll
    for (int mi = 0; mi < 4; ++mi) {
        const float4 bb = *reinterpret_cast<const float4*>(
                              &b1[wl * 64 + mi * 16 + l4 * 4]);
        #pragma unroll
        for (int ni = 0; ni < 2; ++ni) {
            float v0 = acc[mi][ni][0] + bb.x; v0 = v0 > 0.f ? v0 : 0.f;
            float v1 = acc[mi][ni][1] + bb.y; v1 = v1 > 0.f ? v1 : 0.f;
            float v2 = acc[mi][ni][2] + bb.z; v2 = v2 > 0.f ? v2 : 0.f;
            float v3 = acc[mi][ni][3] + bb.w; v3 = v3 > 0.f ? v3 : 0.f;
            u32x2 d;
            d.x = f2bf(v0) | ((unsigned)f2bf(v1) << 16);
            d.y = f2bf(v2) | ((unsigned)f2bf(v3) << 16);
            int row = ni * 16 + l15;
            int w0c = wl * 64 + mi * 16 + l4 * 4;
            int byte = (row * 256 + w0c) * 2;
            byte ^= (row & 7) << 4;
            *reinterpret_cast<u32x2*>(reinterpret_cast<char*>(h_s) + byte) = d;
        }
    }
}

// GEMM2 (swapped): wave owns out-cols [wl*32, +32) (2 frags), 32 rows (2 frags).
__device__ __forceinline__ void gemm2(
    const unsigned short* h_s, const unsigned short* __restrict__ W2p,
    f32x4 (&acc)[2][2], int l15, int l4, int wl, const bf16x8 (&w01)[2][2])
{
    #pragma unroll
    for (int mi = 0; mi < 2; ++mi)
        #pragma unroll
        for (int ni = 0; ni < 2; ++ni) acc[mi][ni] = (f32x4){0.f, 0.f, 0.f, 0.f};

    const unsigned short* Wbase = W2p + ((l4 * 128 + wl * 32 + l15) << 3);
    bf16x8 wf[3][2], hf[2][2];
    #pragma unroll
    for (int mi = 0; mi < 2; ++mi) {
        wf[0][mi] = w01[0][mi];
        wf[1][mi] = w01[1][mi];
    }
    #pragma unroll
    for (int ni = 0; ni < 2; ++ni) hf[0][ni] = loadA<256>(h_s, 0, ni, l15, l4);

    #pragma unroll
    for (int ks = 0; ks < 8; ++ks) {
        if (ks + 2 < 8) {
            #pragma unroll
            for (int mi = 0; mi < 2; ++mi)
                wf[(ks + 2) % 3][mi] = *reinterpret_cast<const bf16x8*>(
                    Wbase + (ks + 2) * 4096 + (mi << 7));
        }
        if (ks + 1 < 8) {
            #pragma unroll
            for (int ni = 0; ni < 2; ++ni)
                hf[(ks + 1) & 1][ni] = loadA<256>(h_s, ks + 1, ni, l15, l4);
        }
        __builtin_amdgcn_s_setprio(1);
        #pragma unroll
        for (int mi = 0; mi < 2; ++mi)
            #pragma unroll
            for (int ni = 0; ni < 2; ++ni)
                acc[mi][ni] = __builtin_amdgcn_mfma_f32_16x16x32_bf16(
                                  wf[ks % 3][mi], hf[ks & 1][ni], acc[mi][ni], 0, 0, 0);
        __builtin_amdgcn_s_setprio(0);
    }
}

__global__ __launch_bounds__(512, 4)
void fused_sbc(const int* __restrict__ user_ids,  const int* __restrict__ item_ids,
               const float* __restrict__ user_table, const float* __restrict__ item_table,
               const unsigned short* __restrict__ uW1p, const float* __restrict__ ub1,
               const unsigned short* __restrict__ uW2p, const float* __restrict__ ub2,
               const unsigned short* __restrict__ iW1p, const float* __restrict__ ib1,
               const unsigned short* __restrict__ iW2p, const float* __restrict__ ib2,
               const float* __restrict__ sw, float* __restrict__ out,
               int B, int nn1)
{
    __shared__ __align__(16) unsigned short smem[40960];   // 80 KB -> 2 blk/CU
    unsigned short* e_u = smem;                  // [32][512]  32 KB
    unsigned short* e_i = smem + 16384;          // [32][256]  16 KB
    unsigned short* h_u = smem + 24576;          // [32][256]  16 KB
    unsigned short* h_i = smem + 32768;          // [32][256]  16 KB
    float* V_lds = reinterpret_cast<float*>(smem);          // [32][132] over e_u
    float* red   = reinterpret_cast<float*>(smem + 16384);  // [4][32][3] over e_i

    const int tid  = threadIdx.x;
    const int lane = tid & 63;
    const int w    = tid >> 6;
    const int l15  = lane & 15, l4 = lane >> 4;
    const int role = w >> 2;                     // 0 = user, 1 = item
    const int wl   = w & 3;
    const int row0 = blockIdx.x * 32;

    const unsigned short* W1sel = role ? iW1p : uW1p;
    const unsigned short* W2sel = role ? iW2p : uW2p;

    // preload BOTH GEMM1 weight rotation slots (hidden under the HBM gather)
    bf16x8 w1pre[2][4];
    {
        const unsigned short* base = W1sel + ((l4 * 256 + wl * 64 + l15) << 3);
        #pragma unroll
        for (int s = 0; s < 2; ++s)
            #pragma unroll
            for (int mi = 0; mi < 4; ++mi)
                w1pre[s][mi] = *reinterpret_cast<const bf16x8*>(
                                   base + s * 8192 + (mi << 7));
    }
    stage_emb<8>(user_ids, user_table, e_u, row0, tid);
    stage_emb<4>(item_ids, item_table, e_i, row0, tid);
    __syncthreads();                             // B1: embeddings staged

    if (role == 0) gemm1<512>(e_u, h_u, uW1p, ub1, l15, l4, wl, w1pre);
    else           gemm1<256>(e_i, h_i, iW1p, ib1, l15, l4, wl, w1pre);

    // preload BOTH GEMM2 slots (in flight across barrier B2)
    bf16x8 w2pre[2][2];
    {
        const unsigned short* base = W2sel + ((l4 * 128 + wl * 32 + l15) << 3);
        #pragma unroll
        for (int s = 0; s < 2; ++s)
            #pragma unroll
            for (int mi = 0; mi < 2; ++mi)
                w2pre[s][mi] = *reinterpret_cast<const bf16x8*>(
                                   base + s * 4096 + (mi << 7));
    }
    __syncthreads();                             // B2: h_u, h_i ready

    f32x4 acc2[2][2];
    if (role == 0) gemm2(h_u, uW2p, acc2, l15, l4, wl, w2pre);
    else           gemm2(h_i, iW2p, acc2, l15, l4, wl, w2pre);

    // item waves: relu(V) -> V_lds + ||v||^2 partials
    if (role == 1) {
        float pv[2] = {0.f, 0.f};
        #pragma unroll
        for (int mi = 0; mi < 2; ++mi) {
            const int colb = wl * 32 + mi * 16 + l4 * 4;
            const float4 bv = *reinterpret_cast<const float4*>(&ib2[colb]);
            #pragma unroll
            for (int ni = 0; ni < 2; ++ni) {
                int row = ni * 16 + l15;
                float v0 = acc2[mi][ni][0] + bv.x; v0 = v0 > 0.f ? v0 : 0.f;
                float v1 = acc2[mi][ni][1] + bv.y; v1 = v1 > 0.f ? v1 : 0.f;
                float v2 = acc2[mi][ni][2] + bv.z; v2 = v2 > 0.f ? v2 : 0.f;
                float v3 = acc2[mi][ni][3] + bv.w; v3 = v3 > 0.f ? v3 : 0.f;
                float4 vv = {v0, v1, v2, v3};
                *reinterpret_cast<float4*>(&V_lds[row * 132 + colb]) = vv;
                pv[ni] += v0 * v0 + v1 * v1 + v2 * v2 + v3 * v3;
            }
        }
        #pragma unroll
        for (int ni = 0; ni < 2; ++ni) {
            pv[ni] += __shfl_xor(pv[ni], 16);
            pv[ni] += __shfl_xor(pv[ni], 32);
        }
        if (l4 == 0) {
            #pragma unroll
            for (int ni = 0; ni < 2; ++ni)
                red[(wl * 32 + ni * 16 + l15) * 3 + 2] = pv[ni];
        }
    }
    __syncthreads();                             // B3: V published

    // user waves: relu(U), dot + ||u||^2 partials
    if (role == 0) {
        float pd[2] = {0.f, 0.f}, pu[2] = {0.f, 0.f};
        #pragma unroll
        for (int mi = 0; mi < 2; ++mi) {
            const int colb = wl * 32 + mi * 16 + l4 * 4;
            const float4 bu = *reinterpret_cast<const float4*>(&ub2[colb]);
            #pragma unroll
            for (int ni = 0; ni < 2; ++ni) {
                int row = ni * 16 + l15;
                float u0 = acc2[mi][ni][0] + bu.x; u0 = u0 > 0.f ? u0 : 0.f;
                float u1 = acc2[mi][ni][1] + bu.y; u1 = u1 > 0.f ? u1 : 0.f;
                float u2 = acc2[mi][ni][2] + bu.z; u2 = u2 > 0.f ? u2 : 0.f;
                float u3 = acc2[mi][ni][3] + bu.w; u3 = u3 > 0.f ? u3 : 0.f;
                const float4 vv = *reinterpret_cast<const float4*>(
                                      &V_lds[row * 132 + colb]);
                pd[ni] += u0 * vv.x + u1 * vv.y + u2 * vv.z + u3 * vv.w;
                pu[ni] += u0 * u0 + u1 * u1 + u2 * u2 + u3 * u3;
            }
        }
        #pragma unroll
        for (int ni = 0; ni < 2; ++ni) {
            pd[ni] += __shfl_xor(pd[ni], 16);
            pd[ni] += __shfl_xor(pd[ni], 32);
            pu[ni] += __shfl_xor(pu[ni], 16);
            pu[ni] += __shfl_xor(pu[ni], 32);
        }
        if (l4 == 0) {
            #pragma unroll
            for (int ni = 0; ni < 2; ++ni) {
                red[(wl * 32 + ni * 16 + l15) * 3 + 0] = pd[ni];
                red[(wl * 32 + ni * 16 + l15) * 3 + 1] = pu[ni];
            }
        }
    }
    __syncthreads();                             // B4: partials in red

    // final reduce + y + scatter
    if (tid < 32) {
        int row = tid;
        float d = 0.f, su = 0.f, sv = 0.f;
        #pragma unroll
        for (int cg = 0; cg < 4; ++cg) {
            d  += red[(cg * 32 + row) * 3 + 0];
            su += red[(cg * 32 + row) * 3 + 1];
            sv += red[(cg * 32 + row) * 3 + 2];
        }
        float un = fmaxf(sqrtf(su), CEPS);
        float vn = fmaxf(sqrtf(sv), CEPS);
        int grow = row0 + row;
        float yv = d / (un * vn) - logf(sw[grow]);
        for (int j = 0; j < nn1; ++j) {
            int idx = grow - j;
            if (idx < 0) idx += B;
            out[idx * nn1 + j] = yv;
        }
    }
}

extern "C" void kernel_launch(void* const* d_in, const int* in_sizes, int n_in,
                              void* d_out, int out_size, void* d_ws, size_t ws_size,
                              hipStream_t stream)
{
    const int*   user_ids   = (const int*)  d_in[0];
    const int*   item_ids   = (const int*)  d_in[1];
    const float* sw         = (const float*)d_in[2];
    const float* user_table = (const float*)d_in[3];
    const float* item_table = (const float*)d_in[4];
    const float* uW1        = (const float*)d_in[5];
    const float* ub1        = (const float*)d_in[6];
    const float* uW2        = (const float*)d_in[7];
    const float* ub2        = (const float*)d_in[8];
    const float* iW1        = (const float*)d_in[9];
    const float* ib1        = (const float*)d_in[10];
    const float* iW2        = (const float*)d_in[11];
    const float* ib2        = (const float*)d_in[12];

    const int B   = in_sizes[2];       // 16384
    const int nn1 = out_size / B;      // n_neg + 1

    unsigned short* wp   = (unsigned short*)d_ws;
    unsigned short* uW1p = wp;               // 131072
    unsigned short* uW2p = wp + 131072;      // 32768
    unsigned short* iW1p = wp + 163840;      // 65536
    unsigned short* iW2p = wp + 229376;      // 32768
    float* out = (float*)d_out;

    pack_all<<<128, 256, 0, stream>>>(uW1, uW2, iW1, iW2,
                                      uW1p, uW2p, iW1p, iW2p);
    fused_sbc<<<B / 32, 512, 0, stream>>>(user_ids, item_ids,
                                          user_table, item_table,
                                          uW1p, ub1, uW2p, ub2,
                                          iW1p, ib1, iW2p, ib2,
                                          sw, out, B, nn1);
}